// Round 4
// baseline (1469.347 us; speedup 1.0000x reference)
//
#include <hip/hip_runtime.h>
#include <hip/hip_bf16.h>

#define B_ 4
#define S_ 2048
#define E_ 1024
#define H_ 16
#define D_ 64

typedef __bf16 bf16x8 __attribute__((ext_vector_type(8)));
typedef __bf16 bf16x4 __attribute__((ext_vector_type(4)));
typedef float  f32x4  __attribute__((ext_vector_type(4)));

__device__ __forceinline__ void gl_lds16(const void* g, void* l) {
  __builtin_amdgcn_global_load_lds((const __attribute__((address_space(1))) void*)g,
                                   (__attribute__((address_space(3))) void*)l, 16, 0, 0);
}

// ---------------------------------------------------------------------------
// LayerNorm over E_=1024; optional fp32 out and bf16 hi/lo split outputs.
__global__ __launch_bounds__(256) void ln_kernel(const float* __restrict__ x,
                                                 const float* __restrict__ g,
                                                 const float* __restrict__ b,
                                                 float* __restrict__ o,
                                                 __bf16* __restrict__ ohi,
                                                 __bf16* __restrict__ olo) {
  int row = blockIdx.x;
  int t = threadIdx.x;
  const float* xr = x + (size_t)row * E_;
  float4 v = *(const float4*)(xr + t * 4);
  float s  = v.x + v.y + v.z + v.w;
  float ss = v.x * v.x + v.y * v.y + v.z * v.z + v.w * v.w;
#pragma unroll
  for (int off = 1; off < 64; off <<= 1) {
    s  += __shfl_xor(s, off);
    ss += __shfl_xor(ss, off);
  }
  __shared__ float sh[8];
  if ((t & 63) == 0) { sh[t >> 6] = s; sh[4 + (t >> 6)] = ss; }
  __syncthreads();
  s  = sh[0] + sh[1] + sh[2] + sh[3];
  ss = sh[4] + sh[5] + sh[6] + sh[7];
  float mu  = s * (1.0f / E_);
  float var = ss * (1.0f / E_) - mu * mu;
  float rstd = rsqrtf(var + 1e-5f);
  float4 gg = *(const float4*)(g + t * 4);
  float4 bb = *(const float4*)(b + t * 4);
  float ov[4];
  ov[0] = (v.x - mu) * rstd * gg.x + bb.x;
  ov[1] = (v.y - mu) * rstd * gg.y + bb.y;
  ov[2] = (v.z - mu) * rstd * gg.z + bb.z;
  ov[3] = (v.w - mu) * rstd * gg.w + bb.w;
  size_t base = (size_t)row * E_ + t * 4;
  if (o) *(float4*)(o + base) = make_float4(ov[0], ov[1], ov[2], ov[3]);
  if (ohi) {
    bf16x4 hv, lv;
#pragma unroll
    for (int j = 0; j < 4; ++j) {
      __bf16 hh = (__bf16)ov[j];
      hv[j] = hh;
      lv[j] = (__bf16)(ov[j] - (float)hh);
    }
    *(bf16x4*)(ohi + base) = hv;
    *(bf16x4*)(olo + base) = lv;
  }
}

// ---------------------------------------------------------------------------
// fp32 -> bf16 hi/lo split, float4 grid-stride.
__global__ __launch_bounds__(256) void split_kernel(const float* __restrict__ in,
                                                    __bf16* __restrict__ hi,
                                                    __bf16* __restrict__ lo,
                                                    int n4) {
  int idx = blockIdx.x * 256 + threadIdx.x;
  int stride = gridDim.x * 256;
  for (int i = idx; i < n4; i += stride) {
    float4 v = ((const float4*)in)[i];
    bf16x4 hv, lv;
#pragma unroll
    for (int j = 0; j < 4; ++j) {
      float f = (&v.x)[j];
      __bf16 hh = (__bf16)f;
      hv[j] = hh;
      lv[j] = (__bf16)(f - (float)hh);
    }
    ((bf16x4*)hi)[i] = hv;
    ((bf16x4*)lo)[i] = lv;
  }
}

// ---------------------------------------------------------------------------
// Pipelined split-bf16 MFMA GEMM (virtual-K over 3 products).
// C[8192,N] = epi( (Ah+Al) @ (Bh+Bl)^T ), products (Ah,Bh),(Ah,Bl),(Al,Bh).
// BMx256 tile, BK=64, 512 thr = 8 waves (2M x 4N), per-wave (BM/2)x64 output.
// LDS unit layout (16B units): A: u = kg*BM + row; B: u = kg*256 + col ->
// linear global_load_lds staging AND consecutive-unit ds_read_b128 (0 bank
// conflicts, proven in round 3). Double-buffered; counted vmcnt(2) keeps
// next-tile loads in flight across raw s_barriers (never drains); 4 phases
// x 16 MFMA with setprio around each cluster.
// Epilogue: qkv mode -> segment (Q*0.125 | K | V-transposed) bf16 hi/lo;
// standard -> bias, optional gelu, optional fp32 residual, fp32 or hi/lo out.
template <int BM>
__global__ __launch_bounds__(512, 2) void gemm3(
    const __bf16* __restrict__ Ah, const __bf16* __restrict__ Al,
    const __bf16* __restrict__ Bh, const __bf16* __restrict__ Bl,
    int N, int K,
    const float* __restrict__ b0, const float* __restrict__ b1,
    const float* __restrict__ b2,
    const float* __restrict__ res, float* __restrict__ Cf,
    __bf16* __restrict__ C0h, __bf16* __restrict__ C0l,
    __bf16* __restrict__ C1h, __bf16* __restrict__ C1l,
    __bf16* __restrict__ C2h, __bf16* __restrict__ C2l,
    int act, int qkv) {
  constexpr int MI    = BM / 32;            // M-fragment count per wave
  constexpr int MPP   = MI / 4;             // mi per phase
  constexpr int AR    = BM / 64;            // A staging rounds
  constexpr int RND   = AR + 4;             // total rounds (A + B)
  constexpr int AU    = BM * 8;             // A units per buffer
  constexpr int BUFU  = AU + 2048;          // units per buffer (A+B)
  constexpr int MTLOG = (BM == 256) ? 5 : 6;  // log2(8192/BM)
  constexpr int LOGBM = (BM == 256) ? 8 : 7;

  __shared__ bf16x8 lds[2 * BUFU];          // 128 KiB (BM=256) / 96 KiB (128)

  const int t = threadIdx.x;
  const int l = t & 63;
  const int w = t >> 6;
  const int wr = w >> 2, wc = w & 3;        // 2M x 4N wave grid
  const int fr = l & 15, kq = l >> 4;

  // bijective XCD swizzle (all grids are multiples of 8)
  const int nwg = gridDim.x;
  const int cpx = nwg >> 3;
  const int bid = blockIdx.x;
  const int swz = (bid & 7) * cpx + (bid >> 3);
  const int mt  = swz & ((1 << MTLOG) - 1);
  const int ntl = swz >> MTLOG;
  const int row0 = mt * BM, col0 = ntl * 256;

  const int ktp = K >> 6;                   // K-tiles per product
  const int nt3 = 3 * ktp;

  f32x4 acc[MI][4];
#pragma unroll
  for (int i = 0; i < MI; ++i)
#pragma unroll
    for (int j = 0; j < 4; ++j) acc[i][j] = (f32x4){0.f, 0.f, 0.f, 0.f};

  auto STAGE = [&](const __bf16* Ax, const __bf16* Bx, int k0, int q, int buf) {
    if (q < AR) {
      int u = q * 512 + t;
      int row = u & (BM - 1), kg = u >> LOGBM;
      gl_lds16(Ax + (size_t)(row0 + row) * K + k0 + kg * 8,
               &lds[buf * BUFU + q * 512 + (t & 448)]);
    } else {
      int qb = q - AR;
      int u = qb * 512 + t;
      int col = u & 255, kg = u >> 8;
      gl_lds16(Bx + (size_t)(col0 + col) * K + k0 + kg * 8,
               &lds[buf * BUFU + AU + qb * 512 + (t & 448)]);
    }
  };

  // prologue: stage tile 0 (product 0, k0=0) into buffer 0
#pragma unroll
  for (int q = 0; q < RND; ++q) STAGE(Ah, Bh, 0, q, 0);

  int cur = 0;
  int k0n = 64, pn = 0;                     // (k0, product) of tile kt+1
  if (ktp == 1) { k0n = 0; pn = 1; }

  for (int kt = 0; kt < nt3; ++kt) {
    const bool notlast = (kt + 1 < nt3);
    const __bf16* An = (pn == 2) ? Al : Ah;
    const __bf16* Bn = (pn == 1) ? Bl : Bh;
    const int nxt = cur ^ 1;
    bf16x8 bfr[4][2];
#pragma unroll
    for (int p = 0; p < 4; ++p) {
      // issue next-tile staging (2 rounds/phase; these stay in flight)
      if (notlast) {
        if (2 * p < RND)     STAGE(An, Bn, k0n, 2 * p, nxt);
        if (2 * p + 1 < RND) STAGE(An, Bn, k0n, 2 * p + 1, nxt);
      }
      if (p == 0) {
        // wait for THIS tile's loads only; leave the 2 just-issued in flight
        if (notlast) asm volatile("s_waitcnt vmcnt(2)" ::: "memory");
        else         asm volatile("s_waitcnt vmcnt(0)" ::: "memory");
        __builtin_amdgcn_s_barrier();
        asm volatile("" ::: "memory");
#pragma unroll
        for (int ni = 0; ni < 4; ++ni)
#pragma unroll
          for (int ks = 0; ks < 2; ++ks)
            bfr[ni][ks] = lds[cur * BUFU + AU + (ks * 4 + kq) * 256 + wc * 64 + ni * 16 + fr];
      }
      bf16x8 af[MPP][2];
#pragma unroll
      for (int mm = 0; mm < MPP; ++mm)
#pragma unroll
        for (int ks = 0; ks < 2; ++ks)
          af[mm][ks] = lds[cur * BUFU + (ks * 4 + kq) * BM + wr * (BM / 2) + (p * MPP + mm) * 16 + fr];
      __builtin_amdgcn_s_setprio(1);
#pragma unroll
      for (int mm = 0; mm < MPP; ++mm)
#pragma unroll
        for (int ni = 0; ni < 4; ++ni)
#pragma unroll
          for (int ks = 0; ks < 2; ++ks)
            acc[p * MPP + mm][ni] = __builtin_amdgcn_mfma_f32_16x16x32_bf16(
                af[mm][ks], bfr[ni][ks], acc[p * MPP + mm][ni], 0, 0, 0);
      __builtin_amdgcn_s_setprio(0);
    }
    asm volatile("" ::: "memory");
    __builtin_amdgcn_s_barrier();           // all waves done reading cur
    asm volatile("" ::: "memory");
    cur = nxt;
    k0n += 64;
    if (k0n == K) { k0n = 0; ++pn; }
  }

  // epilogue: C/D frag col = lane&15 (fr), row = (lane>>4)*4 + r
#pragma unroll
  for (int mi = 0; mi < MI; ++mi) {
    const int rowb = row0 + wr * (BM / 2) + mi * 16 + kq * 4;
#pragma unroll
    for (int ni = 0; ni < 4; ++ni) {
      const int col = col0 + wc * 64 + ni * 16 + fr;
#pragma unroll
      for (int r = 0; r < 4; ++r) {
        const int grow = rowb + r;
        float v = acc[mi][ni][r];
        if (qkv) {
          const int seg = col >> 10, ci = col & 1023;
          float bias = (seg == 0) ? b0[ci] : (seg == 1) ? b1[ci] : b2[ci];
          v += bias;
          if (seg == 0) v *= 0.125f;
          __bf16 hh = (__bf16)v;
          __bf16 ll = (__bf16)(v - (float)hh);
          size_t off = (size_t)grow * 1024 + ci;
          if (seg == 0)      { C0h[off] = hh; C0l[off] = ll; }
          else if (seg == 1) { C1h[off] = hh; C1l[off] = ll; }
          else {
            int bb2 = grow >> 11, ii = grow & 2047;
            int h2i = ci >> 6, dd = ci & 63;
            size_t offt = ((((size_t)bb2 * H_ + h2i) * D_ + dd) << 11) + ii;
            C2h[offt] = hh; C2l[offt] = ll;
          }
        } else {
          v += b0[col];
          if (act) {
            float zn = 0.7978845608028654f * (v + 0.044715f * v * v * v);
            float e = __expf(fminf(2.f * zn, 80.f));
            v = v * e / (e + 1.f);          // 0.5v(1+tanh(zn))
          }
          size_t off = (size_t)grow * N + col;
          if (res) v += res[off];
          if (Cf) Cf[off] = v;
          if (C0h) {
            __bf16 hh = (__bf16)v;
            C0h[off] = hh;
            C0l[off] = (__bf16)(v - (float)hh);
          }
        }
      }
    }
  }
}

// ---------------------------------------------------------------------------
// Sparse flash attention, split-bf16 MFMA (unchanged from round 3).
__device__ __forceinline__ bool sp_allowed(int i, int j) {
  if (j > i) return false;
  bool local;
  if ((i & 127) == 0 && i != 0) local = (j >= i - 128);
  else                          local = (j >= ((i >> 7) << 7));
  int jm = j & 127;
  bool summ = (j >= 96) && ((jm >= 96) || (jm == 0 && j >= 128));
  return local || summ;
}

__global__ __launch_bounds__(256) void attn_mfma(
    const __bf16* __restrict__ qhi, const __bf16* __restrict__ qlo,
    const __bf16* __restrict__ khi, const __bf16* __restrict__ klo,
    const __bf16* __restrict__ vth, const __bf16* __restrict__ vtl,
    __bf16* __restrict__ abhi, __bf16* __restrict__ ablo) {
  const int qt = blockIdx.x;
  const int h  = blockIdx.y;
  const int b  = blockIdx.z;
  const int t = threadIdx.x;
  const int l = t & 63;
  const int w = t >> 6;
  const int lanelo = l & 15, lanehi = l >> 4;

  __shared__ bf16x8 KhL[512], KlL[512], VhL[512], VlL[512];
  __shared__ __align__(16) __bf16 Pl[4][16][72];

  const int arow = qt * 64 + w * 16 + lanelo;
  size_t qoff = ((size_t)(b * S_ + arow)) * E_ + h * D_ + lanehi * 8;
  bf16x8 qh[2], ql[2];
  qh[0] = *(const bf16x8*)(qhi + qoff);      qh[1] = *(const bf16x8*)(qhi + qoff + 32);
  ql[0] = *(const bf16x8*)(qlo + qoff);      ql[1] = *(const bf16x8*)(qlo + qoff + 32);

  const int drow = qt * 64 + w * 16 + lanehi * 4;

  f32x4 o_acc[4];
#pragma unroll
  for (int n = 0; n < 4; ++n) o_acc[n] = (f32x4){0.f, 0.f, 0.f, 0.f};
  float mrow[4] = {-1e30f, -1e30f, -1e30f, -1e30f};
  float lrow[4] = {0.f, 0.f, 0.f, 0.f};

  const int nnear0 = (qt >= 2) ? (qt - 2) : 0;
  const int L = (qt - 2) * 64;
  int tmax = 0, nfar = 0;
  if (L > 96) {
    tmax = (L - 96 + 127) >> 7;
    nfar = (5 * tmax + 7) >> 3;
  }
  const int ntiles = nfar + (qt - nnear0 + 1);

  for (int tile = 0; tile < ntiles; ++tile) {
    const bool is_far = tile < nfar;
    const int jb = nnear0 + (tile - nfar);

    if (w < 2) {
      int c = l, jg; bool valid;
      if (is_far) {
        unsigned g8 = tile * 8 + (c >> 3);
        unsigned t5 = g8 / 5u, u = g8 - t5 * 5u;
        int oo = (int)(u * 8) + (c & 7);
        jg = 96 + ((int)t5 << 7) + oo;
        valid = (g8 < 5u * (unsigned)tmax) && (oo <= 32) && (jg < L);
      } else { jg = (jb << 6) + c; valid = true; }
      int tok = b * S_ + (valid ? jg : 0);
      const __bf16* src = (w == 0 ? khi : klo) + (size_t)tok * E_ + h * D_;
      bf16x8* dst = (w == 0 ? KhL : KlL);
#pragma unroll
      for (int dg = 0; dg < 8; ++dg) gl_lds16(src + dg * 8, dst + dg * 64);
    } else {
      const __bf16* src = (w == 2 ? vth : vtl) + ((size_t)((b * H_ + h) * D_ + l)) * S_;
      bf16x8* dst = (w == 2 ? VhL : VlL);
#pragma unroll
      for (int jgp = 0; jgp < 8; ++jgp) {
        int j0;
        if (is_far) {
          unsigned g8 = tile * 8 + jgp;
          unsigned t5 = g8 / 5u, u = g8 - t5 * 5u;
          j0 = (g8 < 5u * (unsigned)tmax) ? (96 + ((int)t5 << 7) + (int)u * 8) : 0;
        } else j0 = (jb << 6) + jgp * 8;
        gl_lds16(src + j0, dst + jgp * 64);
      }
    }
    __syncthreads();

    f32x4 s[4];
#pragma unroll
    for (int n = 0; n < 4; ++n) s[n] = (f32x4){0.f, 0.f, 0.f, 0.f};
#pragma unroll
    for (int ks = 0; ks < 2; ++ks) {
#pragma unroll
      for (int n = 0; n < 4; ++n) {
        bf16x8 kb_h = KhL[(4 * ks + lanehi) * 64 + n * 16 + lanelo];
        bf16x8 kb_l = KlL[(4 * ks + lanehi) * 64 + n * 16 + lanelo];
        s[n] = __builtin_amdgcn_mfma_f32_16x16x32_bf16(qh[ks], kb_h, s[n], 0, 0, 0);
        s[n] = __builtin_amdgcn_mfma_f32_16x16x32_bf16(qh[ks], kb_l, s[n], 0, 0, 0);
        s[n] = __builtin_amdgcn_mfma_f32_16x16x32_bf16(ql[ks], kb_h, s[n], 0, 0, 0);
      }
    }

    int jgc[4]; bool vldc[4], summc[4];
#pragma unroll
    for (int n = 0; n < 4; ++n) {
      int c = n * 16 + lanelo;
      if (is_far) {
        unsigned g8 = tile * 8 + (c >> 3);
        unsigned t5 = g8 / 5u, u = g8 - t5 * 5u;
        int oo = (int)(u * 8) + (c & 7);
        int jg = 96 + ((int)t5 << 7) + oo;
        jgc[n] = jg;
        vldc[n] = (g8 < 5u * (unsigned)tmax) && (oo <= 32) && (jg < L);
        summc[n] = true;
      } else {
        int jg = (jb << 6) + c;
        jgc[n] = jg; vldc[n] = true;
        int jm = jg & 127;
        summc[n] = (jg >= 96) && ((jm >= 96) || (jm == 0 && jg >= 128));
      }
    }
    float tm[4] = {-1e30f, -1e30f, -1e30f, -1e30f};
#pragma unroll
    for (int r = 0; r < 4; ++r) {
      int i = drow + r;
      int lb = (((i & 127) == 0) && i != 0) ? (i - 128) : ((i >> 7) << 7);
#pragma unroll
      for (int n = 0; n < 4; ++n) {
        bool ok = is_far ? vldc[n]
                         : ((jgc[n] <= i) && ((jgc[n] >= lb) || summc[n]));
        float sv = ok ? s[n][r] : -1e30f;
        s[n][r] = sv;
        tm[r] = fmaxf(tm[r], sv);
      }
    }
#pragma unroll
    for (int off = 1; off < 16; off <<= 1)
#pragma unroll
      for (int r = 0; r < 4; ++r) tm[r] = fmaxf(tm[r], __shfl_xor(tm[r], off));

    float psum[4] = {0.f, 0.f, 0.f, 0.f};
#pragma unroll
    for (int r = 0; r < 4; ++r) {
      float mnew = fmaxf(mrow[r], tm[r]);
      float alpha = __expf(mrow[r] - mnew);
      mrow[r] = mnew;
      lrow[r] *= alpha;
#pragma unroll
      for (int n = 0; n < 4; ++n) o_acc[n][r] *= alpha;
#pragma unroll
      for (int n = 0; n < 4; ++n) {
        float sv = s[n][r];
        float p = (sv > -1e29f) ? __expf(sv - mnew) : 0.f;
        s[n][r] = p;
        psum[r] += p;
      }
    }
#pragma unroll
    for (int off = 1; off < 16; off <<= 1)
#pragma unroll
      for (int r = 0; r < 4; ++r) psum[r] += __shfl_xor(psum[r], off);
#pragma unroll
    for (int r = 0; r < 4; ++r) lrow[r] += psum[r];

#pragma unroll
    for (int r = 0; r < 4; ++r)
#pragma unroll
      for (int n = 0; n < 4; ++n)
        Pl[w][lanehi * 4 + r][n * 16 + lanelo] = (__bf16)s[n][r];
    bf16x8 pa[2];
    pa[0] = *(const bf16x8*)&Pl[w][lanelo][8 * lanehi];
    pa[1] = *(const bf16x8*)&Pl[w][lanelo][8 * lanehi + 32];

#pragma unroll
    for (int ks = 0; ks < 2; ++ks) {
#pragma unroll
      for (int n = 0; n < 4; ++n) {
        bf16x8 vb_h = VhL[(4 * ks + lanehi) * 64 + n * 16 + lanelo];
        bf16x8 vb_l = VlL[(4 * ks + lanehi) * 64 + n * 16 + lanelo];
        o_acc[n] = __builtin_amdgcn_mfma_f32_16x16x32_bf16(pa[ks], vb_h, o_acc[n], 0, 0, 0);
        o_acc[n] = __builtin_amdgcn_mfma_f32_16x16x32_bf16(pa[ks], vb_l, o_acc[n], 0, 0, 0);
      }
    }
    __syncthreads();
  }

#pragma unroll
  for (int r = 0; r < 4; ++r) {
    float inv = 1.0f / lrow[r];
    int i = drow + r;
    size_t rb = ((size_t)(b * S_ + i)) * E_ + h * D_;
#pragma unroll
    for (int n = 0; n < 4; ++n) {
      float val = o_acc[n][r] * inv;
      __bf16 hh = (__bf16)val;
      abhi[rb + n * 16 + lanelo] = hh;
      ablo[rb + n * 16 + lanelo] = (__bf16)(val - (float)hh);
    }
  }
}

// ---------------------------------------------------------------------------
extern "C" void kernel_launch(void* const* d_in, const int* in_sizes, int n_in,
                              void* d_out, int out_size, void* d_ws, size_t ws_size,
                              hipStream_t stream) {
  const float* x      = (const float*)d_in[0];
  const float* ln1_g  = (const float*)d_in[1];
  const float* ln1_b  = (const float*)d_in[2];
  const float* ln2_g  = (const float*)d_in[3];
  const float* ln2_b  = (const float*)d_in[4];
  const float* wq     = (const float*)d_in[5];
  const float* bq     = (const float*)d_in[6];
  const float* wk     = (const float*)d_in[7];
  const float* bk     = (const float*)d_in[8];
  const float* wv     = (const float*)d_in[9];
  const float* bv     = (const float*)d_in[10];
  const float* wo     = (const float*)d_in[11];
  const float* bo     = (const float*)d_in[12];
  const float* w_fc   = (const float*)d_in[13];
  const float* b_fc   = (const float*)d_in[14];
  const float* w_proj = (const float*)d_in[15];
  const float* b_proj = (const float*)d_in[16];
  // d_in[17] = mask — computed in closed form in-kernel.

  char* W = (char*)d_ws;
  const size_t MB = (size_t)1 << 20;
  const int NTOK = B_ * S_;  // 8192

  // Workspace (MiB offsets, 224 total):
  // [0,32)    h fp32            -> l2o_hi [0,16) + l2o_lo [16,32) after WO
  // [32,64)   h_hi/h_lo         -> ab_hi/ab_lo after QKV -> wfc/wpj after WO
  // [64,96)   q_hi/q_lo         -> h2 fp32 after attn
  // [96,128)  k_hi/k_lo         -> fcb_hi [96,160) after attn
  // [128,160) vt_hi/vt_lo
  // [160,176) wqkv+wo scratch   -> fcb_lo [160,224) after WO
  float*  h      = (float*)(W + 0 * MB);
  __bf16* h_hi   = (__bf16*)(W + 32 * MB);
  __bf16* h_lo   = (__bf16*)(W + 48 * MB);
  __bf16* q_hi   = (__bf16*)(W + 64 * MB);
  __bf16* q_lo   = (__bf16*)(W + 80 * MB);
  __bf16* k_hi   = (__bf16*)(W + 96 * MB);
  __bf16* k_lo   = (__bf16*)(W + 112 * MB);
  __bf16* vt_hi  = (__bf16*)(W + 128 * MB);
  __bf16* vt_lo  = (__bf16*)(W + 144 * MB);
  __bf16* ab_hi  = h_hi;
  __bf16* ab_lo  = h_lo;
  float*  h2     = (float*)(W + 64 * MB);
  __bf16* l2o_hi = (__bf16*)(W + 0 * MB);
  __bf16* l2o_lo = (__bf16*)(W + 16 * MB);
  __bf16* fcb_hi = (__bf16*)(W + 96 * MB);
  __bf16* fcb_lo = (__bf16*)(W + 160 * MB);
  __bf16* wqkv_hi = (__bf16*)(W + 160 * MB);  // [3072,1024] bf16 = 6 MiB
  __bf16* wqkv_lo = (__bf16*)(W + 166 * MB);
  __bf16* wo_hi  = (__bf16*)(W + 172 * MB);
  __bf16* wo_lo  = (__bf16*)(W + 174 * MB);
  __bf16* wfc_hi = (__bf16*)(W + 32 * MB);
  __bf16* wfc_lo = (__bf16*)(W + 40 * MB);
  __bf16* wpj_hi = (__bf16*)(W + 32 * MB);
  __bf16* wpj_lo = (__bf16*)(W + 40 * MB);
  float* out = (float*)d_out;

  const int SPLIT_BLKS = 2048;
  const int nw1 = E_ * E_ / 4;
  const int nw4 = 4 * E_ * E_ / 4;
  const int WSEG = E_ * E_;  // elements per weight segment in wqkv

  // LN1 -> h fp32 + bf16 split
  ln_kernel<<<NTOK, 256, 0, stream>>>(x, ln1_g, ln1_b, h, h_hi, h_lo);

  // fused QKV: weights concatenated [wq; wk; wv] -> [3072,1024]
  split_kernel<<<SPLIT_BLKS, 256, 0, stream>>>(wq, wqkv_hi, wqkv_lo, nw1);
  split_kernel<<<SPLIT_BLKS, 256, 0, stream>>>(wk, wqkv_hi + WSEG, wqkv_lo + WSEG, nw1);
  split_kernel<<<SPLIT_BLKS, 256, 0, stream>>>(wv, wqkv_hi + 2 * WSEG, wqkv_lo + 2 * WSEG, nw1);
  gemm3<256><<<384, 512, 0, stream>>>(h_hi, h_lo, wqkv_hi, wqkv_lo, 3072, E_,
                                      bq, bk, bv, nullptr, nullptr,
                                      q_hi, q_lo, k_hi, k_lo, vt_hi, vt_lo, 0, 1);

  // sparse attention
  attn_mfma<<<dim3(S_ / 64, H_, B_), 256, 0, stream>>>(q_hi, q_lo, k_hi, k_lo,
                                                       vt_hi, vt_lo, ab_hi, ab_lo);

  // WO projection + residual(h) -> h2 (fp32)
  split_kernel<<<SPLIT_BLKS, 256, 0, stream>>>(wo, wo_hi, wo_lo, nw1);
  gemm3<128><<<256, 512, 0, stream>>>(ab_hi, ab_lo, wo_hi, wo_lo, E_, E_,
                                      bo, nullptr, nullptr, h, h2,
                                      nullptr, nullptr, nullptr, nullptr, nullptr, nullptr, 0, 0);

  // LN2 -> bf16 split only
  ln_kernel<<<NTOK, 256, 0, stream>>>(h2, ln2_g, ln2_b, nullptr, l2o_hi, l2o_lo);

  // FC + GELU -> bf16 hi/lo
  split_kernel<<<SPLIT_BLKS, 256, 0, stream>>>(w_fc, wfc_hi, wfc_lo, nw4);
  gemm3<256><<<512, 512, 0, stream>>>(l2o_hi, l2o_lo, wfc_hi, wfc_lo, 4 * E_, E_,
                                      b_fc, nullptr, nullptr, nullptr, nullptr,
                                      fcb_hi, fcb_lo, nullptr, nullptr, nullptr, nullptr, 1, 0);

  // PROJ + residual(h2) -> out (fp32)
  split_kernel<<<SPLIT_BLKS, 256, 0, stream>>>(w_proj, wpj_hi, wpj_lo, nw4);
  gemm3<128><<<256, 512, 0, stream>>>(fcb_hi, fcb_lo, wpj_hi, wpj_lo, E_, 4 * E_,
                                      b_proj, nullptr, nullptr, h2, out,
                                      nullptr, nullptr, nullptr, nullptr, nullptr, nullptr, 0, 0);
}